// Round 6
// baseline (93.139 us; speedup 1.0000x reference)
//
#include <hip/hip_runtime.h>
#include <hip/hip_bf16.h>

typedef __attribute__((ext_vector_type(8))) short short8;
typedef __attribute__((ext_vector_type(8))) _Float16 half8;
typedef __attribute__((ext_vector_type(2))) _Float16 h2;
typedef __attribute__((ext_vector_type(4))) float f32x4;

#define NFACE 16384
#define NBATCH 8
#define CIN 128
#define COUT 128
#define KGEMM 512
#define MBLK 128                       // faces per block
#define GRID ((NBATCH * NFACE) / MBLK) // 1024, divisible by 8
#define LDW 136                        // W_lds row stride in halfs (128 + 8)
#define LDA 136                        // fcv row stride in halfs (128 + 8)

__device__ __forceinline__ unsigned short f2bf(float x) {
    union { float f; unsigned u; } v; v.f = x;
    unsigned r = v.u + 0x7fffu + ((v.u >> 16) & 1u);  // RNE
    return (unsigned short)(r >> 16);
}
__device__ __forceinline__ unsigned pack2bf(float lo, float hi) {
    return (unsigned)f2bf(lo) | ((unsigned)f2bf(hi) << 16);
}

__device__ __forceinline__ h2 habs2(h2 x) {
    union { h2 h; unsigned u; } v; v.h = x; v.u &= 0x7fff7fffu; return v.h;
}
__device__ __forceinline__ unsigned h2u(h2 x) {
    union { h2 h; unsigned u; } v; v.h = x; return v.u;
}
__device__ __forceinline__ h2 u2h(unsigned x) {
    union { h2 h; unsigned u; } v; v.u = x; return v.h;
}

// ---- features fp32 -> packed f16 (linear grid, NO swizzle — R5's swizzle caused
// remote-dirty L2 lines: FETCH 34->75 MB, WRITE 66->194 MB) ----
__global__ void fconv_kernel(const float* __restrict__ f, unsigned* __restrict__ o, int n4) {
    int i = blockIdx.x * 256 + threadIdx.x;  // one uint4 (8 floats -> 8 halfs)
    if (i >= n4) return;
    const float4* fp = (const float4*)f;
    float4 a = fp[i * 2], b = fp[i * 2 + 1];
    h2 p0 = {(_Float16)a.x, (_Float16)a.y};
    h2 p1 = {(_Float16)a.z, (_Float16)a.w};
    h2 p2 = {(_Float16)b.x, (_Float16)b.y};
    h2 p3 = {(_Float16)b.z, (_Float16)b.w};
    uint4 r; r.x = h2u(p0); r.y = h2u(p1); r.z = h2u(p2); r.w = h2u(p3);
    ((uint4*)o)[i] = r;
}

// ---- weight fp32 (o,c,1,4) -> f16, chunked kk-major K: wbt2[o][ (c>>5)*128 + kk*32 + (c&31) ] ----
__global__ void wconv2_kernel(const float* __restrict__ w, _Float16* __restrict__ bt2) {
    int i = blockIdx.x * 256 + threadIdx.x;  // one (o,c) pair = 4 floats
    if (i >= COUT * CIN) return;
    int o = i >> 7, c = i & 127;
    float4 wv = ((const float4*)w)[i];
    _Float16* dst = bt2 + (size_t)o * KGEMM + (c >> 5) * 128 + (c & 31);
    dst[0]  = (_Float16)wv.x;
    dst[32] = (_Float16)wv.y;
    dst[64] = (_Float16)wv.z;
    dst[96] = (_Float16)wv.w;
}

// ---- old-layout bf16 weight (fallback path): bt[o][kk*128+c] ----
__global__ void wconv_kernel(const float* __restrict__ w, unsigned short* __restrict__ bt) {
    int i = blockIdx.x * 256 + threadIdx.x;
    if (i >= COUT * CIN) return;
    int o = i >> 7, c = i & 127;
#pragma unroll
    for (int kk = 0; kk < 4; ++kk)
        bt[o * KGEMM + kk * CIN + c] = f2bf(w[(o * CIN + c) * 4 + kk]);
}

__global__ __launch_bounds__(512, 2)
void meshconv_v6(const unsigned* __restrict__ featf16,
                 const int* __restrict__ ring,
                 const _Float16* __restrict__ wbt2,
                 const float* __restrict__ bias,
                 float* __restrict__ out)
{
    __shared__ _Float16 Wl[COUT * LDW];   // 34 KiB: weight K-chunk (kk-major local K)
    __shared__ _Float16 Al[MBLK * LDA];   // 34 KiB: fcv K-chunk
    __shared__ int ridx[MBLK * 6];        // 3 KiB

    const int t = threadIdx.x;
    // batch-per-XCD swizzle (proven good in R4: FETCH 34 MB)
    const int bid = (blockIdx.x & 7) * (GRID / 8) + (blockIdx.x >> 3);
    const int base = bid * MBLK;
    const int batch = bid >> 7;

    if (t < 192)  // 128 faces * 6 ints = 192 uint4
        ((uint4*)ridx)[t] = ((const uint4*)(ring + (size_t)base * 6))[t];
    __syncthreads();

    // GEMM mapping: 8 waves = 4 face-tiles (32 faces) x 2 col-halves (64 cols)
    const int w  = t >> 6;
    const int l  = t & 63;
    const int lo = l & 15;
    const int hi = l >> 4;
    const int wr = w >> 1;
    const int wc = w & 1;

    // build mapping: thread = (face fq = t>>2, channel-octet c8 = t&3 within chunk)
    const int fq = t >> 2;
    const int c8 = t & 3;
    const char* __restrict__ fbb = (const char*)featf16 + (size_t)batch * NFACE * 256;
    int offs[6];
    {
        const int* ri = &ridx[fq * 6];
#pragma unroll
        for (int j = 0; j < 6; ++j) offs[j] = ri[j] * 256 + c8 * 16;
    }
    // W-stage mapping: thread = (o = t>>2, seg = t&3), 64 B per thread
    const int wo = t >> 2, wseg = t & 3;
    const char* __restrict__ wsrc = (const char*)(wbt2 + (size_t)wo * KGEMM + wseg * 32);

    f32x4 acc[2][4];
#pragma unroll
    for (int rt = 0; rt < 2; ++rt)
#pragma unroll
        for (int ct = 0; ct < 4; ++ct)
            acc[rt][ct] = (f32x4){0.f, 0.f, 0.f, 0.f};

    // ---- prologue: issue chunk-0 loads ----
    uint4 wpre[4], gpre[6];
#pragma unroll
    for (int s = 0; s < 4; ++s) wpre[s] = *(const uint4*)(wsrc + s * 16);
#pragma unroll
    for (int j = 0; j < 6; ++j) gpre[j] = *(const uint4*)(fbb + offs[j]);

#pragma unroll
    for (int ch = 0; ch < 4; ++ch) {
        // ---- consume prefetched regs ----
        uint4 wreg[4], n[6];
#pragma unroll
        for (int s = 0; s < 4; ++s) wreg[s] = wpre[s];
#pragma unroll
        for (int j = 0; j < 6; ++j) n[j] = gpre[j];

        // ---- build fcv chunk: packed f16 math, kk-major K-local layout ----
        {
            unsigned f1w[4], f2w[4], f3w[4];
#pragma unroll
            for (int q = 0; q < 4; ++q) {  // q = word = channels 2q,2q+1
                h2 x0 = u2h(((const unsigned*)&n[0])[q]);
                h2 x1 = u2h(((const unsigned*)&n[1])[q]);
                h2 x2 = u2h(((const unsigned*)&n[2])[q]);
                h2 x3 = u2h(((const unsigned*)&n[3])[q]);
                h2 x4 = u2h(((const unsigned*)&n[4])[q]);
                h2 x5 = u2h(((const unsigned*)&n[5])[q]);
                h2 s = x1 + x2; s = s + x3; s = s + x4; s = s + x5;
                h2 five = {(_Float16)5.0f, (_Float16)5.0f};
                h2 d = habs2(five * x0 - s);
                h2 t3 = habs2(x1 - x2) + habs2(x1 - x3);
                t3 = t3 + habs2(x1 - x4); t3 = t3 + habs2(x1 - x5);
                t3 = t3 + habs2(x2 - x3); t3 = t3 + habs2(x2 - x4);
                t3 = t3 + habs2(x2 - x5); t3 = t3 + habs2(x3 - x4);
                t3 = t3 + habs2(x3 - x5); t3 = t3 + habs2(x4 - x5);
                f1w[q] = h2u(s); f2w[q] = h2u(d); f3w[q] = h2u(t3);
            }
            // A-row chunk-local layout: halfs [kk*32 + c'], c' = c8*8 + (0..7)
            _Float16* row = &Al[fq * LDA + c8 * 8];
            *(uint4*)&row[0]  = n[0];                                    // kk=0: n0
            *(uint4*)&row[32] = (uint4){f1w[0], f1w[1], f1w[2], f1w[3]}; // kk=1
            *(uint4*)&row[64] = (uint4){f2w[0], f2w[1], f2w[2], f2w[3]}; // kk=2
            *(uint4*)&row[96] = (uint4){f3w[0], f3w[1], f3w[2], f3w[3]}; // kk=3
        }
        // ---- write W chunk to LDS ----
        {
            uint4* dst = (uint4*)&Wl[wo * LDW + wseg * 32];
#pragma unroll
            for (int s = 0; s < 4; ++s) dst[s] = wreg[s];
        }
        __syncthreads();

        // ---- issue next chunk's loads (hide under GEMM) ----
        if (ch < 3) {
#pragma unroll
            for (int s = 0; s < 4; ++s)
                wpre[s] = *(const uint4*)(wsrc + (ch + 1) * 256 + s * 16);
#pragma unroll
            for (int j = 0; j < 6; ++j)
                gpre[j] = *(const uint4*)(fbb + offs[j] + (ch + 1) * 64);
        }

        // ---- GEMM on chunk: K=128 = 4 ksteps of 32 ----
#pragma unroll
        for (int ks = 0; ks < 4; ++ks) {
            const int k0 = ks * 32 + hi * 8;
            half8 a0 = *(const half8*)&Al[(wr * 32 + lo) * LDA + k0];
            half8 a1 = *(const half8*)&Al[(wr * 32 + 16 + lo) * LDA + k0];
#pragma unroll
            for (int ct = 0; ct < 4; ++ct) {
                half8 b = *(const half8*)&Wl[(wc * 64 + ct * 16 + lo) * LDW + k0];
                acc[0][ct] = __builtin_amdgcn_mfma_f32_16x16x32_f16(a0, b, acc[0][ct], 0, 0, 0);
                acc[1][ct] = __builtin_amdgcn_mfma_f32_16x16x32_f16(a1, b, acc[1][ct], 0, 0, 0);
            }
        }
        __syncthreads();
    }

    // ---- epilogue: + bias, store fp32 ----
    const int col0 = wc * 64;
    float bo[4];
#pragma unroll
    for (int ct = 0; ct < 4; ++ct) bo[ct] = bias[col0 + ct * 16 + lo];
#pragma unroll
    for (int rt = 0; rt < 2; ++rt) {
#pragma unroll
        for (int ct = 0; ct < 4; ++ct) {
#pragma unroll
            for (int v = 0; v < 4; ++v) {
                const int r = base + wr * 32 + rt * 16 + hi * 4 + v;  // C/D: row=(l>>4)*4+v, col=l&15
                out[(size_t)r * COUT + col0 + ct * 16 + lo] = acc[rt][ct][v] + bo[ct];
            }
        }
    }
}

// fallback (ws too small): fp32 gather, bf16 MFMA, old weight layout
__global__ __launch_bounds__(256, 4)
void meshconv_ref(const float* __restrict__ feat,
                  const int* __restrict__ ring,
                  const unsigned short* __restrict__ wbt,
                  const float* __restrict__ bias,
                  float* __restrict__ out)
{
#define RMBLK 32
#define RLDF 520
    __shared__ unsigned short fcv[RMBLK * RLDF];
    __shared__ int ridx[RMBLK * 6];

    const int t = threadIdx.x;
    const int bid = (blockIdx.x & 7) * (4096 / 8) + (blockIdx.x >> 3);
    const int base = bid * RMBLK;
    const int batch = base >> 14;

    for (int i = t; i < RMBLK * 6; i += 256)
        ridx[i] = ring[(size_t)base * 6 + i];
    __syncthreads();

    {
        const int c2 = t & 63;
        const int fq = t >> 6;
        const float2* fb = (const float2*)feat + (size_t)batch * NFACE * 64;
        for (int it = 0; it < RMBLK / 4; ++it) {
            const int fl = it * 4 + fq;
            const int* ri = &ridx[fl * 6];
            float nl[6], nh[6];
#pragma unroll
            for (int j = 0; j < 6; ++j) {
                float2 u = fb[(size_t)ri[j] * 64 + c2];
                nl[j] = u.x; nh[j] = u.y;
            }
            float fc1l = nl[1] + nl[2] + nl[3] + nl[4] + nl[5];
            float fc1h = nh[1] + nh[2] + nh[3] + nh[4] + nh[5];
            float fc2l = fabsf(5.0f * nl[0] - fc1l);
            float fc2h = fabsf(5.0f * nh[0] - fc1h);
            float fc3l = 0.f, fc3h = 0.f;
#pragma unroll
            for (int a = 1; a < 5; ++a)
#pragma unroll
                for (int b = a + 1; b < 6; ++b) {
                    fc3l += fabsf(nl[a] - nl[b]);
                    fc3h += fabsf(nh[a] - nh[b]);
                }
            unsigned* row = (unsigned*)&fcv[fl * RLDF];
            row[c2]       = pack2bf(nl[0], nh[0]);
            row[64 + c2]  = pack2bf(fc1l, fc1h);
            row[128 + c2] = pack2bf(fc2l, fc2h);
            row[192 + c2] = pack2bf(fc3l, fc3h);
        }
    }
    __syncthreads();

    const int w  = t >> 6;
    const int l  = t & 63;
    const int lo = l & 15;
    const int hi = l >> 4;
    const int col0 = w * 32;

    f32x4 acc[2][2];
#pragma unroll
    for (int rt = 0; rt < 2; ++rt)
#pragma unroll
        for (int ct = 0; ct < 2; ++ct)
            acc[rt][ct] = (f32x4){0.f, 0.f, 0.f, 0.f};

    const unsigned short* __restrict__ wb0 = wbt + (size_t)(col0 + lo) * KGEMM;

    for (int ks = 0; ks < 16; ++ks) {
        const int k0 = ks * 32 + hi * 8;
        short8 a0 = *(const short8*)&fcv[(0 * 16 + lo) * RLDF + k0];
        short8 a1 = *(const short8*)&fcv[(1 * 16 + lo) * RLDF + k0];
        short8 b0 = *(const short8*)&wb0[k0];
        short8 b1 = *(const short8*)&wb0[16 * KGEMM + k0];
        acc[0][0] = __builtin_amdgcn_mfma_f32_16x16x32_bf16(a0, b0, acc[0][0], 0, 0, 0);
        acc[1][0] = __builtin_amdgcn_mfma_f32_16x16x32_bf16(a1, b0, acc[1][0], 0, 0, 0);
        acc[0][1] = __builtin_amdgcn_mfma_f32_16x16x32_bf16(a0, b1, acc[0][1], 0, 0, 0);
        acc[1][1] = __builtin_amdgcn_mfma_f32_16x16x32_bf16(a1, b1, acc[1][1], 0, 0, 0);
    }

    const float bo0 = bias[col0 + lo];
    const float bo1 = bias[col0 + 16 + lo];
#pragma unroll
    for (int rt = 0; rt < 2; ++rt) {
#pragma unroll
        for (int v = 0; v < 4; ++v) {
            const int r = base + rt * 16 + hi * 4 + v;
            out[(size_t)r * COUT + col0 + lo]      = acc[rt][0][v] + bo0;
            out[(size_t)r * COUT + col0 + 16 + lo] = acc[rt][1][v] + bo1;
        }
    }
}

__global__ void zero_kernel(const int* __restrict__ zm, const int* __restrict__ zf,
                            float* __restrict__ out) {
    const int i = blockIdx.x;
    const size_t face = (size_t)zm[i] * NFACE + zf[i];
    out[face * COUT + threadIdx.x] = 0.0f;
}

extern "C" void kernel_launch(void* const* d_in, const int* in_sizes, int n_in,
                              void* d_out, int out_size, void* d_ws, size_t ws_size,
                              hipStream_t stream) {
    const float* feat = (const float*)d_in[0];
    const int*   ring = (const int*)d_in[1];
    const float* wgt  = (const float*)d_in[2];
    const float* bias = (const float*)d_in[3];
    const int*   zm   = (const int*)d_in[4];
    const int*   zf   = (const int*)d_in[5];
    float* out = (float*)d_out;

    const size_t feath_bytes = (size_t)NBATCH * NFACE * CIN * 2;  // 32 MiB
    const size_t wbt_bytes = (size_t)COUT * KGEMM * 2;            // 128 KiB
    const bool use_f16 = ws_size >= feath_bytes + wbt_bytes;

    if (use_f16) {
        unsigned* feath = (unsigned*)d_ws;
        _Float16* wbt2 = (_Float16*)((char*)d_ws + feath_bytes);
        const int n4 = NBATCH * NFACE * CIN / 8;
        hipLaunchKernelGGL(fconv_kernel, dim3((n4 + 255) / 256), dim3(256), 0, stream,
                           feat, feath, n4);
        hipLaunchKernelGGL(wconv2_kernel, dim3((COUT * CIN + 255) / 256), dim3(256), 0, stream,
                           wgt, wbt2);
        hipLaunchKernelGGL(meshconv_v6, dim3(GRID), dim3(512), 0, stream,
                           feath, ring, wbt2, bias, out);
    } else {
        unsigned short* wbt = (unsigned short*)d_ws;
        hipLaunchKernelGGL(wconv_kernel, dim3((COUT * CIN + 255) / 256), dim3(256), 0, stream,
                           wgt, wbt);
        hipLaunchKernelGGL(meshconv_ref, dim3(4096), dim3(256), 0, stream,
                           feat, ring, wbt, bias, out);
    }
    hipLaunchKernelGGL(zero_kernel, dim3(1024), dim3(128), 0, stream, zm, zf, out);
}

// Round 7
// 62.087 us; speedup vs baseline: 1.5001x; 1.5001x over previous
//
#include <hip/hip_runtime.h>
#include <hip/hip_bf16.h>

typedef __attribute__((ext_vector_type(8))) short short8;
typedef __attribute__((ext_vector_type(8))) _Float16 half8;
typedef __attribute__((ext_vector_type(2))) _Float16 h2;
typedef __attribute__((ext_vector_type(4))) float f32x4;

#define NFACE 16384
#define NBATCH 8
#define CIN 128
#define COUT 128
#define KGEMM 512
#define MBLK 128                       // faces per block
#define GRID ((NBATCH * NFACE) / MBLK) // 1024, divisible by 8
#define LDW 136                        // W_lds row stride in halfs (128 + 8)
#define LDA 136                        // fcv row stride in halfs (128 + 8)

__device__ __forceinline__ unsigned short f2bf(float x) {
    union { float f; unsigned u; } v; v.f = x;
    unsigned r = v.u + 0x7fffu + ((v.u >> 16) & 1u);  // RNE
    return (unsigned short)(r >> 16);
}
__device__ __forceinline__ unsigned pack2bf(float lo, float hi) {
    return (unsigned)f2bf(lo) | ((unsigned)f2bf(hi) << 16);
}

__device__ __forceinline__ h2 habs2(h2 x) {
    union { h2 h; unsigned u; } v; v.h = x; v.u &= 0x7fff7fffu; return v.h;
}
__device__ __forceinline__ unsigned h2u(h2 x) {
    union { h2 h; unsigned u; } v; v.h = x; return v.u;
}
__device__ __forceinline__ h2 u2h(unsigned x) {
    union { h2 h; unsigned u; } v; v.u = x; return v.h;
}

// ---- features fp32 -> packed f16 (linear grid) ----
__global__ void fconv_kernel(const float* __restrict__ f, unsigned* __restrict__ o, int n4) {
    int i = blockIdx.x * 256 + threadIdx.x;  // one uint4 (8 floats -> 8 halfs)
    if (i >= n4) return;
    const float4* fp = (const float4*)f;
    float4 a = fp[i * 2], b = fp[i * 2 + 1];
    h2 p0 = {(_Float16)a.x, (_Float16)a.y};
    h2 p1 = {(_Float16)a.z, (_Float16)a.w};
    h2 p2 = {(_Float16)b.x, (_Float16)b.y};
    h2 p3 = {(_Float16)b.z, (_Float16)b.w};
    uint4 r; r.x = h2u(p0); r.y = h2u(p1); r.z = h2u(p2); r.w = h2u(p3);
    ((uint4*)o)[i] = r;
}

// ---- weight fp32 (o,c,1,4) -> f16, chunked kk-major K: wbt2[o][ (c>>5)*128 + kk*32 + (c&31) ] ----
__global__ void wconv2_kernel(const float* __restrict__ w, _Float16* __restrict__ bt2) {
    int i = blockIdx.x * 256 + threadIdx.x;  // one (o,c) pair = 4 floats
    if (i >= COUT * CIN) return;
    int o = i >> 7, c = i & 127;
    float4 wv = ((const float4*)w)[i];
    _Float16* dst = bt2 + (size_t)o * KGEMM + (c >> 5) * 128 + (c & 31);
    dst[0]  = (_Float16)wv.x;
    dst[32] = (_Float16)wv.y;
    dst[64] = (_Float16)wv.z;
    dst[96] = (_Float16)wv.w;
}

// ---- old-layout bf16 weight (fallback path): bt[o][kk*128+c] ----
__global__ void wconv_kernel(const float* __restrict__ w, unsigned short* __restrict__ bt) {
    int i = blockIdx.x * 256 + threadIdx.x;
    if (i >= COUT * CIN) return;
    int o = i >> 7, c = i & 127;
#pragma unroll
    for (int kk = 0; kk < 4; ++kk)
        bt[o * KGEMM + kk * CIN + c] = f2bf(w[(o * CIN + c) * 4 + kk]);
}

// R7 = R4's direct-staging chunk loop (NO register prefetch held across GEMM —
// R5/R6's prefetch caused scratch spills: WRITE 66->194 MB, FETCH 34->69 MB)
// + R5's f16 packed build / kk-major layouts / f16 MFMA (VALUBusy 32->12%).
__global__ __launch_bounds__(512, 2)
void meshconv_v7(const unsigned* __restrict__ featf16,
                 const int* __restrict__ ring,
                 const _Float16* __restrict__ wbt2,
                 const float* __restrict__ bias,
                 float* __restrict__ out)
{
    __shared__ _Float16 Wl[COUT * LDW];   // 34 KiB: weight K-chunk (kk-major local K)
    __shared__ _Float16 Al[MBLK * LDA];   // 34 KiB: fcv K-chunk
    __shared__ int ridx[MBLK * 6];        // 3 KiB

    const int t = threadIdx.x;
    // batch-per-XCD swizzle (proven good in R4: FETCH 34 MB)
    const int bid = (blockIdx.x & 7) * (GRID / 8) + (blockIdx.x >> 3);
    const int base = bid * MBLK;
    const int batch = bid >> 7;

    if (t < 192)  // 128 faces * 6 ints = 192 uint4
        ((uint4*)ridx)[t] = ((const uint4*)(ring + (size_t)base * 6))[t];
    __syncthreads();

    // GEMM mapping: 8 waves = 4 face-tiles (32 faces) x 2 col-halves (64 cols)
    const int w  = t >> 6;
    const int l  = t & 63;
    const int lo = l & 15;
    const int hi = l >> 4;
    const int wr = w >> 1;
    const int wc = w & 1;

    // build mapping: thread = (face fq = t>>2, channel-octet c8 = t&3 within chunk)
    const int fq = t >> 2;
    const int c8 = t & 3;
    const char* __restrict__ fbb = (const char*)featf16 + (size_t)batch * NFACE * 256;
    int offs[6];
    {
        const int* ri = &ridx[fq * 6];
#pragma unroll
        for (int j = 0; j < 6; ++j) offs[j] = ri[j] * 256 + c8 * 16;
    }
    // W-stage mapping: thread = (o = t>>2, seg = t&3), 64 B per thread
    const int wo = t >> 2, wseg = t & 3;
    const char* __restrict__ wsrc = (const char*)(wbt2 + (size_t)wo * KGEMM + wseg * 32);

    f32x4 acc[2][4];
#pragma unroll
    for (int rt = 0; rt < 2; ++rt)
#pragma unroll
        for (int ct = 0; ct < 4; ++ct)
            acc[rt][ct] = (f32x4){0.f, 0.f, 0.f, 0.f};

    for (int ch = 0; ch < 4; ++ch) {
        if (ch) __syncthreads();  // WAR: previous GEMM reads done before overwrite

        // ---- stage weight K-chunk directly (short-lived regs) ----
        {
            const uint4* src = (const uint4*)(wsrc + ch * 256);
            uint4* dst = (uint4*)&Wl[wo * LDW + wseg * 32];
            uint4 v0 = src[0], v1 = src[1], v2 = src[2], v3 = src[3];
            dst[0] = v0; dst[1] = v1; dst[2] = v2; dst[3] = v3;
        }

        // ---- gather 6 neighbor 16-B segments, build fcv chunk (8 channels) ----
        {
            uint4 n[6];
#pragma unroll
            for (int j = 0; j < 6; ++j)
                n[j] = *(const uint4*)(fbb + offs[j] + ch * 64);

            unsigned f1w[4], f2w[4], f3w[4];
#pragma unroll
            for (int q = 0; q < 4; ++q) {  // q = word = channels 2q,2q+1
                h2 x0 = u2h(((const unsigned*)&n[0])[q]);
                h2 x1 = u2h(((const unsigned*)&n[1])[q]);
                h2 x2 = u2h(((const unsigned*)&n[2])[q]);
                h2 x3 = u2h(((const unsigned*)&n[3])[q]);
                h2 x4 = u2h(((const unsigned*)&n[4])[q]);
                h2 x5 = u2h(((const unsigned*)&n[5])[q]);
                h2 s = x1 + x2; s = s + x3; s = s + x4; s = s + x5;
                h2 five = {(_Float16)5.0f, (_Float16)5.0f};
                h2 d = habs2(five * x0 - s);
                h2 t3 = habs2(x1 - x2) + habs2(x1 - x3);
                t3 = t3 + habs2(x1 - x4); t3 = t3 + habs2(x1 - x5);
                t3 = t3 + habs2(x2 - x3); t3 = t3 + habs2(x2 - x4);
                t3 = t3 + habs2(x2 - x5); t3 = t3 + habs2(x3 - x4);
                t3 = t3 + habs2(x3 - x5); t3 = t3 + habs2(x4 - x5);
                f1w[q] = h2u(s); f2w[q] = h2u(d); f3w[q] = h2u(t3);
            }
            // A-row chunk-local layout: halfs [kk*32 + c'], c' = c8*8 + (0..7)
            _Float16* row = &Al[fq * LDA + c8 * 8];
            *(uint4*)&row[0]  = n[0];                                    // kk=0: n0
            *(uint4*)&row[32] = (uint4){f1w[0], f1w[1], f1w[2], f1w[3]}; // kk=1
            *(uint4*)&row[64] = (uint4){f2w[0], f2w[1], f2w[2], f2w[3]}; // kk=2
            *(uint4*)&row[96] = (uint4){f3w[0], f3w[1], f3w[2], f3w[3]}; // kk=3
        }
        __syncthreads();

        // ---- GEMM on chunk: K=128 = 4 ksteps of 32 ----
#pragma unroll
        for (int ks = 0; ks < 4; ++ks) {
            const int k0 = ks * 32 + hi * 8;
            half8 a0 = *(const half8*)&Al[(wr * 32 + lo) * LDA + k0];
            half8 a1 = *(const half8*)&Al[(wr * 32 + 16 + lo) * LDA + k0];
#pragma unroll
            for (int ct = 0; ct < 4; ++ct) {
                half8 b = *(const half8*)&Wl[(wc * 64 + ct * 16 + lo) * LDW + k0];
                acc[0][ct] = __builtin_amdgcn_mfma_f32_16x16x32_f16(a0, b, acc[0][ct], 0, 0, 0);
                acc[1][ct] = __builtin_amdgcn_mfma_f32_16x16x32_f16(a1, b, acc[1][ct], 0, 0, 0);
            }
        }
    }

    // ---- epilogue: + bias, store fp32 ----
    const int col0 = wc * 64;
    float bo[4];
#pragma unroll
    for (int ct = 0; ct < 4; ++ct) bo[ct] = bias[col0 + ct * 16 + lo];
#pragma unroll
    for (int rt = 0; rt < 2; ++rt) {
#pragma unroll
        for (int ct = 0; ct < 4; ++ct) {
#pragma unroll
            for (int v = 0; v < 4; ++v) {
                const int r = base + wr * 32 + rt * 16 + hi * 4 + v;  // C/D: row=(l>>4)*4+v, col=l&15
                out[(size_t)r * COUT + col0 + ct * 16 + lo] = acc[rt][ct][v] + bo[ct];
            }
        }
    }
}

// fallback (ws too small): fp32 gather, bf16 MFMA, old weight layout
__global__ __launch_bounds__(256, 4)
void meshconv_ref(const float* __restrict__ feat,
                  const int* __restrict__ ring,
                  const unsigned short* __restrict__ wbt,
                  const float* __restrict__ bias,
                  float* __restrict__ out)
{
#define RMBLK 32
#define RLDF 520
    __shared__ unsigned short fcv[RMBLK * RLDF];
    __shared__ int ridx[RMBLK * 6];

    const int t = threadIdx.x;
    const int bid = (blockIdx.x & 7) * (4096 / 8) + (blockIdx.x >> 3);
    const int base = bid * RMBLK;
    const int batch = base >> 14;

    for (int i = t; i < RMBLK * 6; i += 256)
        ridx[i] = ring[(size_t)base * 6 + i];
    __syncthreads();

    {
        const int c2 = t & 63;
        const int fq = t >> 6;
        const float2* fb = (const float2*)feat + (size_t)batch * NFACE * 64;
        for (int it = 0; it < RMBLK / 4; ++it) {
            const int fl = it * 4 + fq;
            const int* ri = &ridx[fl * 6];
            float nl[6], nh[6];
#pragma unroll
            for (int j = 0; j < 6; ++j) {
                float2 u = fb[(size_t)ri[j] * 64 + c2];
                nl[j] = u.x; nh[j] = u.y;
            }
            float fc1l = nl[1] + nl[2] + nl[3] + nl[4] + nl[5];
            float fc1h = nh[1] + nh[2] + nh[3] + nh[4] + nh[5];
            float fc2l = fabsf(5.0f * nl[0] - fc1l);
            float fc2h = fabsf(5.0f * nh[0] - fc1h);
            float fc3l = 0.f, fc3h = 0.f;
#pragma unroll
            for (int a = 1; a < 5; ++a)
#pragma unroll
                for (int b = a + 1; b < 6; ++b) {
                    fc3l += fabsf(nl[a] - nl[b]);
                    fc3h += fabsf(nh[a] - nh[b]);
                }
            unsigned* row = (unsigned*)&fcv[fl * RLDF];
            row[c2]       = pack2bf(nl[0], nh[0]);
            row[64 + c2]  = pack2bf(fc1l, fc1h);
            row[128 + c2] = pack2bf(fc2l, fc2h);
            row[192 + c2] = pack2bf(fc3l, fc3h);
        }
    }
    __syncthreads();

    const int w  = t >> 6;
    const int l  = t & 63;
    const int lo = l & 15;
    const int hi = l >> 4;
    const int col0 = w * 32;

    f32x4 acc[2][2];
#pragma unroll
    for (int rt = 0; rt < 2; ++rt)
#pragma unroll
        for (int ct = 0; ct < 2; ++ct)
            acc[rt][ct] = (f32x4){0.f, 0.f, 0.f, 0.f};

    const unsigned short* __restrict__ wb0 = wbt + (size_t)(col0 + lo) * KGEMM;

    for (int ks = 0; ks < 16; ++ks) {
        const int k0 = ks * 32 + hi * 8;
        short8 a0 = *(const short8*)&fcv[(0 * 16 + lo) * RLDF + k0];
        short8 a1 = *(const short8*)&fcv[(1 * 16 + lo) * RLDF + k0];
        short8 b0 = *(const short8*)&wb0[k0];
        short8 b1 = *(const short8*)&wb0[16 * KGEMM + k0];
        acc[0][0] = __builtin_amdgcn_mfma_f32_16x16x32_bf16(a0, b0, acc[0][0], 0, 0, 0);
        acc[1][0] = __builtin_amdgcn_mfma_f32_16x16x32_bf16(a1, b0, acc[1][0], 0, 0, 0);
        acc[0][1] = __builtin_amdgcn_mfma_f32_16x16x32_bf16(a0, b1, acc[0][1], 0, 0, 0);
        acc[1][1] = __builtin_amdgcn_mfma_f32_16x16x32_bf16(a1, b1, acc[1][1], 0, 0, 0);
    }

    const float bo0 = bias[col0 + lo];
    const float bo1 = bias[col0 + 16 + lo];
#pragma unroll
    for (int rt = 0; rt < 2; ++rt) {
#pragma unroll
        for (int v = 0; v < 4; ++v) {
            const int r = base + rt * 16 + hi * 4 + v;
            out[(size_t)r * COUT + col0 + lo]      = acc[rt][0][v] + bo0;
            out[(size_t)r * COUT + col0 + 16 + lo] = acc[rt][1][v] + bo1;
        }
    }
}

__global__ void zero_kernel(const int* __restrict__ zm, const int* __restrict__ zf,
                            float* __restrict__ out) {
    const int i = blockIdx.x;
    const size_t face = (size_t)zm[i] * NFACE + zf[i];
    out[face * COUT + threadIdx.x] = 0.0f;
}

extern "C" void kernel_launch(void* const* d_in, const int* in_sizes, int n_in,
                              void* d_out, int out_size, void* d_ws, size_t ws_size,
                              hipStream_t stream) {
    const float* feat = (const float*)d_in[0];
    const int*   ring = (const int*)d_in[1];
    const float* wgt  = (const float*)d_in[2];
    const float* bias = (const float*)d_in[3];
    const int*   zm   = (const int*)d_in[4];
    const int*   zf   = (const int*)d_in[5];
    float* out = (float*)d_out;

    const size_t feath_bytes = (size_t)NBATCH * NFACE * CIN * 2;  // 32 MiB
    const size_t wbt_bytes = (size_t)COUT * KGEMM * 2;            // 128 KiB
    const bool use_f16 = ws_size >= feath_bytes + wbt_bytes;

    if (use_f16) {
        unsigned* feath = (unsigned*)d_ws;
        _Float16* wbt2 = (_Float16*)((char*)d_ws + feath_bytes);
        const int n4 = NBATCH * NFACE * CIN / 8;
        hipLaunchKernelGGL(fconv_kernel, dim3((n4 + 255) / 256), dim3(256), 0, stream,
                           feat, feath, n4);
        hipLaunchKernelGGL(wconv2_kernel, dim3((COUT * CIN + 255) / 256), dim3(256), 0, stream,
                           wgt, wbt2);
        hipLaunchKernelGGL(meshconv_v7, dim3(GRID), dim3(512), 0, stream,
                           feath, ring, wbt2, bias, out);
    } else {
        unsigned short* wbt = (unsigned short*)d_ws;
        hipLaunchKernelGGL(wconv_kernel, dim3((COUT * CIN + 255) / 256), dim3(256), 0, stream,
                           wgt, wbt);
        hipLaunchKernelGGL(meshconv_ref, dim3(4096), dim3(256), 0, stream,
                           feat, ring, wbt, bias, out);
    }
    hipLaunchKernelGGL(zero_kernel, dim3(1024), dim3(128), 0, stream, zm, zf, out);
}

// Round 8
// 61.368 us; speedup vs baseline: 1.5177x; 1.0117x over previous
//
#include <hip/hip_runtime.h>
#include <hip/hip_bf16.h>

typedef __attribute__((ext_vector_type(8))) short short8;
typedef __attribute__((ext_vector_type(8))) _Float16 half8;
typedef __attribute__((ext_vector_type(2))) _Float16 h2;
typedef __attribute__((ext_vector_type(4))) float f32x4;

#define NFACE 16384
#define NBATCH 8
#define CIN 128
#define COUT 128
#define KGEMM 512
#define MBLK 256                       // faces per block (2 halves of 128)
#define HALF 128
#define GRID ((NBATCH * NFACE) / MBLK) // 512, divisible by 8
#define LDW 136                        // W_lds row stride in halfs (128 + 8)
#define LDA 136                        // fcv row stride in halfs (128 + 8)

__device__ __forceinline__ unsigned short f2bf(float x) {
    union { float f; unsigned u; } v; v.f = x;
    unsigned r = v.u + 0x7fffu + ((v.u >> 16) & 1u);  // RNE
    return (unsigned short)(r >> 16);
}
__device__ __forceinline__ unsigned pack2bf(float lo, float hi) {
    return (unsigned)f2bf(lo) | ((unsigned)f2bf(hi) << 16);
}

__device__ __forceinline__ h2 habs2(h2 x) {
    union { h2 h; unsigned u; } v; v.h = x; v.u &= 0x7fff7fffu; return v.h;
}
__device__ __forceinline__ unsigned h2u(h2 x) {
    union { h2 h; unsigned u; } v; v.h = x; return v.u;
}
__device__ __forceinline__ h2 u2h(unsigned x) {
    union { h2 h; unsigned u; } v; v.u = x; return v.h;
}

// ---- features fp32 -> packed f16 (linear grid) ----
__global__ void fconv_kernel(const float* __restrict__ f, unsigned* __restrict__ o, int n4) {
    int i = blockIdx.x * 256 + threadIdx.x;  // one uint4 (8 floats -> 8 halfs)
    if (i >= n4) return;
    const float4* fp = (const float4*)f;
    float4 a = fp[i * 2], b = fp[i * 2 + 1];
    h2 p0 = {(_Float16)a.x, (_Float16)a.y};
    h2 p1 = {(_Float16)a.z, (_Float16)a.w};
    h2 p2 = {(_Float16)b.x, (_Float16)b.y};
    h2 p3 = {(_Float16)b.z, (_Float16)b.w};
    uint4 r; r.x = h2u(p0); r.y = h2u(p1); r.z = h2u(p2); r.w = h2u(p3);
    ((uint4*)o)[i] = r;
}

// ---- weight fp32 (o,c,1,4) -> f16, chunked kk-major K: wbt2[o][ (c>>5)*128 + kk*32 + (c&31) ] ----
__global__ void wconv2_kernel(const float* __restrict__ w, _Float16* __restrict__ bt2) {
    int i = blockIdx.x * 256 + threadIdx.x;  // one (o,c) pair = 4 floats
    if (i >= COUT * CIN) return;
    int o = i >> 7, c = i & 127;
    float4 wv = ((const float4*)w)[i];
    _Float16* dst = bt2 + (size_t)o * KGEMM + (c >> 5) * 128 + (c & 31);
    dst[0]  = (_Float16)wv.x;
    dst[32] = (_Float16)wv.y;
    dst[64] = (_Float16)wv.z;
    dst[96] = (_Float16)wv.w;
}

// ---- old-layout bf16 weight (fallback path): bt[o][kk*128+c] ----
__global__ void wconv_kernel(const float* __restrict__ w, unsigned short* __restrict__ bt) {
    int i = blockIdx.x * 256 + threadIdx.x;
    if (i >= COUT * CIN) return;
    int o = i >> 7, c = i & 127;
#pragma unroll
    for (int kk = 0; kk < 4; ++kk)
        bt[o * KGEMM + kk * CIN + c] = f2bf(w[(o * CIN + c) * 4 + kk]);
}

// gather 6 neighbors' 16-B segments for chunk ch, build fcv, store to A row.
// Direct-consume loads (short-lived regs — no prefetch across MFMA: R5/R6 spill lesson).
__device__ __forceinline__ void build_half(const char* __restrict__ fbb,
                                           const int* __restrict__ ri,  // &ridx[(h*128+fq)*6]
                                           int c8, int ch,
                                           _Float16* __restrict__ Arow) {
    uint4 n[6];
#pragma unroll
    for (int j = 0; j < 6; ++j)
        n[j] = *(const uint4*)(fbb + ((size_t)(ri[j] * 256 + c8 * 16 + ch * 64)));

#pragma unroll
    for (int qp = 0; qp < 2; ++qp) {   // q-pairs: {0,1}, {2,3} — trims live regs
        unsigned o0[2], o1[2], o2[2], o3[2];
#pragma unroll
        for (int qi = 0; qi < 2; ++qi) {
            const int q = qp * 2 + qi;
            h2 x0 = u2h(((const unsigned*)&n[0])[q]);
            h2 x1 = u2h(((const unsigned*)&n[1])[q]);
            h2 x2 = u2h(((const unsigned*)&n[2])[q]);
            h2 x3 = u2h(((const unsigned*)&n[3])[q]);
            h2 x4 = u2h(((const unsigned*)&n[4])[q]);
            h2 x5 = u2h(((const unsigned*)&n[5])[q]);
            h2 s = x1 + x2; s = s + x3; s = s + x4; s = s + x5;
            h2 five = {(_Float16)5.0f, (_Float16)5.0f};
            h2 d = habs2(five * x0 - s);
            h2 t3 = habs2(x1 - x2) + habs2(x1 - x3);
            t3 = t3 + habs2(x1 - x4); t3 = t3 + habs2(x1 - x5);
            t3 = t3 + habs2(x2 - x3); t3 = t3 + habs2(x2 - x4);
            t3 = t3 + habs2(x2 - x5); t3 = t3 + habs2(x3 - x4);
            t3 = t3 + habs2(x3 - x5); t3 = t3 + habs2(x4 - x5);
            o0[qi] = ((const unsigned*)&n[0])[q];
            o1[qi] = h2u(s); o2[qi] = h2u(d); o3[qi] = h2u(t3);
        }
        // A-row layout: halfs [kk*32 + c'], c' = c8*8 + 2q
        const int co = c8 * 8 + qp * 4;
        *(uint2*)&Arow[0 * 32 + co] = (uint2){o0[0], o0[1]};
        *(uint2*)&Arow[1 * 32 + co] = (uint2){o1[0], o1[1]};
        *(uint2*)&Arow[2 * 32 + co] = (uint2){o2[0], o2[1]};
        *(uint2*)&Arow[3 * 32 + co] = (uint2){o3[0], o3[1]};
    }
}

__device__ __forceinline__ void gemm_half(const _Float16* __restrict__ Al,
                                          const _Float16* __restrict__ Wl,
                                          int wr, int wc, int lo, int hi,
                                          f32x4 (*acc)[4]) {
#pragma unroll
    for (int ks = 0; ks < 4; ++ks) {
        const int k0 = ks * 32 + hi * 8;
        half8 a0 = *(const half8*)&Al[(wr * 32 + lo) * LDA + k0];
        half8 a1 = *(const half8*)&Al[(wr * 32 + 16 + lo) * LDA + k0];
#pragma unroll
        for (int ct = 0; ct < 4; ++ct) {
            half8 b = *(const half8*)&Wl[(wc * 64 + ct * 16 + lo) * LDW + k0];
            acc[0][ct] = __builtin_amdgcn_mfma_f32_16x16x32_f16(a0, b, acc[0][ct], 0, 0, 0);
            acc[1][ct] = __builtin_amdgcn_mfma_f32_16x16x32_f16(a1, b, acc[1][ct], 0, 0, 0);
        }
    }
}

// v8 = R7 + MBLK 128->256 (two halves share each staged W chunk: W traffic halved)
__global__ __launch_bounds__(512, 4)
void meshconv_v8(const unsigned* __restrict__ featf16,
                 const int* __restrict__ ring,
                 const _Float16* __restrict__ wbt2,
                 const float* __restrict__ bias,
                 float* __restrict__ out)
{
    __shared__ _Float16 Wl[COUT * LDW];   // 34 KiB
    __shared__ _Float16 Al[HALF * LDA];   // 34 KiB (one half at a time)
    __shared__ int ridx[MBLK * 6];        // 6 KiB

    const int t = threadIdx.x;
    // batch-per-XCD swizzle: 64 blocks per batch, one batch per XCD
    const int bid = (blockIdx.x & 7) * (GRID / 8) + (blockIdx.x >> 3);
    const int base = bid * MBLK;
    const int batch = bid >> 6;

    if (t < 384)  // 256 faces * 6 ints = 384 uint4
        ((uint4*)ridx)[t] = ((const uint4*)(ring + (size_t)base * 6))[t];
    __syncthreads();

    // GEMM mapping: 8 waves = 4 face-tiles (32 faces) x 2 col-halves (64 cols)
    const int w  = t >> 6;
    const int l  = t & 63;
    const int lo = l & 15;
    const int hi = l >> 4;
    const int wr = w >> 1;
    const int wc = w & 1;

    // build mapping: thread = (face fq = t>>2, channel-octet c8 = t&3 within chunk)
    const int fq = t >> 2;
    const int c8 = t & 3;
    const char* __restrict__ fbb = (const char*)featf16 + (size_t)batch * NFACE * 256;

    // W-stage mapping: thread = (o = t>>2, seg = t&3), 64 B per thread
    const int wo = t >> 2, wseg = t & 3;
    const char* __restrict__ wsrc = (const char*)(wbt2 + (size_t)wo * KGEMM + wseg * 32);

    f32x4 acc0[2][4], acc1[2][4];
#pragma unroll
    for (int rt = 0; rt < 2; ++rt)
#pragma unroll
        for (int ct = 0; ct < 4; ++ct) {
            acc0[rt][ct] = (f32x4){0.f, 0.f, 0.f, 0.f};
            acc1[rt][ct] = (f32x4){0.f, 0.f, 0.f, 0.f};
        }

    for (int ch = 0; ch < 4; ++ch) {
        if (ch) __syncthreads();  // W + A safe to overwrite (GEMM h1 of prev chunk done)

        // ---- stage weight K-chunk ONCE for both halves ----
        {
            const uint4* src = (const uint4*)(wsrc + ch * 256);
            uint4* dst = (uint4*)&Wl[wo * LDW + wseg * 32];
            uint4 v0 = src[0], v1 = src[1], v2 = src[2], v3 = src[3];
            dst[0] = v0; dst[1] = v1; dst[2] = v2; dst[3] = v3;
        }

        // ---- half 0 ----
        build_half(fbb, &ridx[fq * 6], c8, ch, &Al[fq * LDA]);
        __syncthreads();
        gemm_half(Al, Wl, wr, wc, lo, hi, acc0);
        __syncthreads();  // A reads done

        // ---- half 1 (reuses staged W) ----
        build_half(fbb, &ridx[(HALF + fq) * 6], c8, ch, &Al[fq * LDA]);
        __syncthreads();
        gemm_half(Al, Wl, wr, wc, lo, hi, acc1);
    }

    // ---- epilogue: + bias, store fp32 ----
    const int col0 = wc * 64;
    float bo[4];
#pragma unroll
    for (int ct = 0; ct < 4; ++ct) bo[ct] = bias[col0 + ct * 16 + lo];
#pragma unroll
    for (int rt = 0; rt < 2; ++rt) {
#pragma unroll
        for (int ct = 0; ct < 4; ++ct) {
#pragma unroll
            for (int v = 0; v < 4; ++v) {
                const int r0 = base + wr * 32 + rt * 16 + hi * 4 + v;  // C/D: row=(l>>4)*4+v, col=l&15
                out[(size_t)r0 * COUT + col0 + ct * 16 + lo] = acc0[rt][ct][v] + bo[ct];
                out[(size_t)(r0 + HALF) * COUT + col0 + ct * 16 + lo] = acc1[rt][ct][v] + bo[ct];
            }
        }
    }
}

// fallback (ws too small): fp32 gather, bf16 MFMA, old weight layout
__global__ __launch_bounds__(256, 4)
void meshconv_ref(const float* __restrict__ feat,
                  const int* __restrict__ ring,
                  const unsigned short* __restrict__ wbt,
                  const float* __restrict__ bias,
                  float* __restrict__ out)
{
#define RMBLK 32
#define RLDF 520
    __shared__ unsigned short fcv[RMBLK * RLDF];
    __shared__ int ridx[RMBLK * 6];

    const int t = threadIdx.x;
    const int bid = (blockIdx.x & 7) * (4096 / 8) + (blockIdx.x >> 3);
    const int base = bid * RMBLK;
    const int batch = base >> 14;

    for (int i = t; i < RMBLK * 6; i += 256)
        ridx[i] = ring[(size_t)base * 6 + i];
    __syncthreads();

    {
        const int c2 = t & 63;
        const int fq = t >> 6;
        const float2* fb = (const float2*)feat + (size_t)batch * NFACE * 64;
        for (int it = 0; it < RMBLK / 4; ++it) {
            const int fl = it * 4 + fq;
            const int* ri = &ridx[fl * 6];
            float nl[6], nh[6];
#pragma unroll
            for (int j = 0; j < 6; ++j) {
                float2 u = fb[(size_t)ri[j] * 64 + c2];
                nl[j] = u.x; nh[j] = u.y;
            }
            float fc1l = nl[1] + nl[2] + nl[3] + nl[4] + nl[5];
            float fc1h = nh[1] + nh[2] + nh[3] + nh[4] + nh[5];
            float fc2l = fabsf(5.0f * nl[0] - fc1l);
            float fc2h = fabsf(5.0f * nh[0] - fc1h);
            float fc3l = 0.f, fc3h = 0.f;
#pragma unroll
            for (int a = 1; a < 5; ++a)
#pragma unroll
                for (int b = a + 1; b < 6; ++b) {
                    fc3l += fabsf(nl[a] - nl[b]);
                    fc3h += fabsf(nh[a] - nh[b]);
                }
            unsigned* row = (unsigned*)&fcv[fl * RLDF];
            row[c2]       = pack2bf(nl[0], nh[0]);
            row[64 + c2]  = pack2bf(fc1l, fc1h);
            row[128 + c2] = pack2bf(fc2l, fc2h);
            row[192 + c2] = pack2bf(fc3l, fc3h);
        }
    }
    __syncthreads();

    const int w  = t >> 6;
    const int l  = t & 63;
    const int lo = l & 15;
    const int hi = l >> 4;
    const int col0 = w * 32;

    f32x4 acc[2][2];
#pragma unroll
    for (int rt = 0; rt < 2; ++rt)
#pragma unroll
        for (int ct = 0; ct < 2; ++ct)
            acc[rt][ct] = (f32x4){0.f, 0.f, 0.f, 0.f};

    const unsigned short* __restrict__ wb0 = wbt + (size_t)(col0 + lo) * KGEMM;

    for (int ks = 0; ks < 16; ++ks) {
        const int k0 = ks * 32 + hi * 8;
        short8 a0 = *(const short8*)&fcv[(0 * 16 + lo) * RLDF + k0];
        short8 a1 = *(const short8*)&fcv[(1 * 16 + lo) * RLDF + k0];
        short8 b0 = *(const short8*)&wb0[k0];
        short8 b1 = *(const short8*)&wb0[16 * KGEMM + k0];
        acc[0][0] = __builtin_amdgcn_mfma_f32_16x16x32_bf16(a0, b0, acc[0][0], 0, 0, 0);
        acc[1][0] = __builtin_amdgcn_mfma_f32_16x16x32_bf16(a1, b0, acc[1][0], 0, 0, 0);
        acc[0][1] = __builtin_amdgcn_mfma_f32_16x16x32_bf16(a0, b1, acc[0][1], 0, 0, 0);
        acc[1][1] = __builtin_amdgcn_mfma_f32_16x16x32_bf16(a1, b1, acc[1][1], 0, 0, 0);
    }

    const float bo0 = bias[col0 + lo];
    const float bo1 = bias[col0 + 16 + lo];
#pragma unroll
    for (int rt = 0; rt < 2; ++rt) {
#pragma unroll
        for (int v = 0; v < 4; ++v) {
            const int r = base + rt * 16 + hi * 4 + v;
            out[(size_t)r * COUT + col0 + lo]      = acc[rt][0][v] + bo0;
            out[(size_t)r * COUT + col0 + 16 + lo] = acc[rt][1][v] + bo1;
        }
    }
}

__global__ void zero_kernel(const int* __restrict__ zm, const int* __restrict__ zf,
                            float* __restrict__ out) {
    const int i = blockIdx.x;
    const size_t face = (size_t)zm[i] * NFACE + zf[i];
    out[face * COUT + threadIdx.x] = 0.0f;
}

extern "C" void kernel_launch(void* const* d_in, const int* in_sizes, int n_in,
                              void* d_out, int out_size, void* d_ws, size_t ws_size,
                              hipStream_t stream) {
    const float* feat = (const float*)d_in[0];
    const int*   ring = (const int*)d_in[1];
    const float* wgt  = (const float*)d_in[2];
    const float* bias = (const float*)d_in[3];
    const int*   zm   = (const int*)d_in[4];
    const int*   zf   = (const int*)d_in[5];
    float* out = (float*)d_out;

    const size_t feath_bytes = (size_t)NBATCH * NFACE * CIN * 2;  // 32 MiB
    const size_t wbt_bytes = (size_t)COUT * KGEMM * 2;            // 128 KiB
    const bool use_f16 = ws_size >= feath_bytes + wbt_bytes;

    if (use_f16) {
        unsigned* feath = (unsigned*)d_ws;
        _Float16* wbt2 = (_Float16*)((char*)d_ws + feath_bytes);
        const int n4 = NBATCH * NFACE * CIN / 8;
        hipLaunchKernelGGL(fconv_kernel, dim3((n4 + 255) / 256), dim3(256), 0, stream,
                           feat, feath, n4);
        hipLaunchKernelGGL(wconv2_kernel, dim3((COUT * CIN + 255) / 256), dim3(256), 0, stream,
                           wgt, wbt2);
        hipLaunchKernelGGL(meshconv_v8, dim3(GRID), dim3(512), 0, stream,
                           feath, ring, wbt2, bias, out);
    } else {
        unsigned short* wbt = (unsigned short*)d_ws;
        hipLaunchKernelGGL(wconv_kernel, dim3((COUT * CIN + 255) / 256), dim3(256), 0, stream,
                           wgt, wbt);
        hipLaunchKernelGGL(meshconv_ref, dim3(4096), dim3(256), 0, stream,
                           feat, ring, wbt, bias, out);
    }
    hipLaunchKernelGGL(zero_kernel, dim3(1024), dim3(128), 0, stream, zm, zf, out);
}